// Round 9
// baseline (28.603 us; speedup 1.0000x reference)
//
#include <hip/hip_runtime.h>
#include <math.h>

// Problem constants (from reference setup_inputs)
#define BB 16
#define QQ 900
#define NC 92
#define NCP 96          // padded class count (classes 92..95 have prob 0)
#define TT 1600
#define BQ (BB * QQ)    // 14400

// ---------------------------------------------------------------------------
// R9: R6 structure with transposed prob gather.
//   grid = (BQ/8 = 1800, 1), block = 256 = 4 waves.
//   Wave rg owns RT=2 rows; 64 lanes sweep all 1600 targets (25 iters).
//   LDS: NORMALIZED probs transposed pg[class][row], stride 10 floats
//   (40 B). One ds_read_b64 at &pg[id][rloc] fetches BOTH rows' probs
//   -> gather wave-instrs halve vs R6, and the same-bank row-pair
//   conflict (row stride 384 B in R6 = bank-aligned) is eliminated.
//   Everything else identical to R6 (plain stores, prefetch, unroll 5).
// ---------------------------------------------------------------------------
#define RT 2        // rows per thread (= rows per wave)
#define RTILE 8     // rows per block
#define NK 25       // 25 x 64 targets = 1600

__global__ __launch_bounds__(256)
void k_cost(const float* __restrict__ logits,
            const float* __restrict__ boxes,       // [BQ,4] cxcywh
            const int* __restrict__ tids,          // [TT] int32
            const float* __restrict__ tbox,        // [TT,4] cxcywh
            float* __restrict__ out) {
    __shared__ float pg[NCP][10];                  // [class][row], 3840 B

    const int row0 = blockIdx.x * RTILE;

    // ---- stage unnormalized exp(logit), transposed; classes 92..95 = 0 ----
    #pragma unroll
    for (int it = 0; it < 3; ++it) {               // 3 x 256 = 768 = 8*96
        int idx = it * 256 + threadIdx.x;
        int r = idx / NCP, c = idx - r * NCP;      // c fast -> coalesced read
        float v = 0.0f;
        if (c < NC) v = __expf(logits[(row0 + r) * NC + c]);
        pg[c][r] = v;
    }
    __syncthreads();

    // ---- normalize in place: thread owns (row r, classes 3ls..3ls+2) ----
    {
        const int r  = threadIdx.x >> 5;           // 0..7
        const int ls = threadIdx.x & 31;           // 0..31 (3*31+2 = 95)
        float a = pg[ls * 3][r];
        float b = pg[ls * 3 + 1][r];
        float d = pg[ls * 3 + 2][r];
        float s = a + b + d;
        s += __shfl_xor(s, 1);
        s += __shfl_xor(s, 2);
        s += __shfl_xor(s, 4);
        s += __shfl_xor(s, 8);
        s += __shfl_xor(s, 16);                    // sum over 32-lane half
        float rinv = __builtin_amdgcn_rcpf(s);
        pg[ls * 3][r]     = a * rinv;
        pg[ls * 3 + 1][r] = b * rinv;
        pg[ls * 3 + 2][r] = d * rinv;
    }

    const int tl   = threadIdx.x & 63;
    const int rg   = threadIdx.x >> 6;
    const int rloc = rg * RT;                      // 0,2,4,6 (keeps b64 align)
    const int rbase = row0 + rloc;

    // ---- register-blocked row box data ----
    float rcx[RT], rcy[RT], rw[RT], rh[RT];
    float rx0[RT], ry0[RT], rx1[RT], ry1[RT], rar[RT];
    #pragma unroll
    for (int j = 0; j < RT; ++j) {
        float4 bb = ((const float4*)boxes)[rbase + j];
        rcx[j] = bb.x; rcy[j] = bb.y; rw[j] = bb.z; rh[j] = bb.w;
        rx0[j] = bb.x - 0.5f * bb.z; ry0[j] = bb.y - 0.5f * bb.w;
        rx1[j] = bb.x + 0.5f * bb.z; ry1[j] = bb.y + 0.5f * bb.w;
        rar[j] = bb.z * bb.w;
    }
    __syncthreads();

    // ---- main loop: 25 x 64 targets, prefetch, plain stores ----
    float* o0 = out + rbase * TT + tl;
    float4 tb = ((const float4*)tbox)[tl];
    int    id = tids[tl];
    #pragma unroll 5
    for (int k = 0; k < NK; ++k) {
        float4 tbn; int idn;
        if (k + 1 < NK) {
            tbn = ((const float4*)tbox)[(k + 1) * 64 + tl];
            idn = tids[(k + 1) * 64 + tl];
        }
        // ONE b64 gather: probs for both of this wave's rows
        float2 pp = *(const float2*)&pg[id][rloc];
        float tx0 = tb.x - 0.5f * tb.z, ty0 = tb.y - 0.5f * tb.w;
        float tx1 = tb.x + 0.5f * tb.z, ty1 = tb.y + 0.5f * tb.w;
        float tar = tb.z * tb.w;
        #pragma unroll
        for (int j = 0; j < RT; ++j) {
            // L1 cdist in cxcywh space
            float l1 = fabsf(rcx[j] - tb.x) + fabsf(rcy[j] - tb.y)
                     + fabsf(rw[j]  - tb.z) + fabsf(rh[j]  - tb.w);
            // unclamped intersection extents
            float iwu = fminf(rx1[j], tx1) - fmaxf(rx0[j], tx0);
            float ihu = fminf(ry1[j], ty1) - fmaxf(ry0[j], ty0);
            float inter = fmaxf(iwu, 0.0f) * fmaxf(ihu, 0.0f);
            float uni = rar[j] + tar - inter;
            // enclosing box via min+max identity (always non-negative)
            float ew = (rw[j] + tb.z) - iwu;
            float eh = (rh[j] + tb.w) - ihu;
            float ea = ew * eh;
            // giou = (ea*(inter-uni) + uni^2) / (uni*ea), single rcp
            float num = fmaf(ea, inter - uni, uni * uni);
            float rden = __builtin_amdgcn_rcpf(uni * ea);
            // C = 5*l1 - p - 2*giou   (p normalized; static .x/.y select)
            float p = (j == 0) ? pp.x : pp.y;
            float c = fmaf(5.0f, l1, -p);
            c = fmaf(-2.0f * num, rden, c);
            o0[j * TT + k * 64] = c;
        }
        tb = tbn; id = idn;
    }
}

// ---------------------------------------------------------------------------
extern "C" void kernel_launch(void* const* d_in, const int* in_sizes, int n_in,
                              void* d_out, int out_size, void* d_ws, size_t ws_size,
                              hipStream_t stream) {
    const float* logits = (const float*)d_in[0];   // [16,900,92] f32
    const float* boxes  = (const float*)d_in[1];   // [16,900,4]  f32
    const int*   tids   = (const int*)  d_in[2];   // [1600] int32
    const float* tbox   = (const float*)d_in[3];   // [1600,4] f32
    float* out = (float*)d_out;

    k_cost<<<dim3(BQ / RTILE, 1), 256, 0, stream>>>(
        logits, boxes, tids, tbox, out);
}